// Round 6
// baseline (609.511 us; speedup 1.0000x reference)
//
#include <hip/hip_runtime.h>
#include <hip/hip_bf16.h>

// ---------------------------------------------------------------------------
// Spiking Swin block: QKV(+LIF) -> binary attention (+rpb) -> PV -> proj(+LIF)
// I/O: float32. MFMA bf16 16x16x32 for GEMM work (exact for 0/1 spikes).
//
// Index facts (flat-order-preserving reshapes, verified by R2/R3/R5 absmax=0):
//  - group g = t*256 + b_old = b_new*4 + head; bits uint32[g][n] over d.
//  - attn flat = (g*256 + n)*256 + m   (f32 output)
//  - out0 flat = t2*2097152 + b_new*8192 + hw*128 + c, n = t2*64 + hw
//
// R5 lesson: occupancy/NT-store tweaks on k_attn are neutral -> it is
// store-BW-bound. This round: fuse proj into k_attn via per-b atomic
// counters (split-K-style last-arriver pattern) so proj overlaps the attn
// tail; agent-scope fences handle cross-XCD L2 non-coherence.
// ---------------------------------------------------------------------------

typedef __attribute__((ext_vector_type(8))) short bf16x8;   // 8 bf16 = 4 VGPRs
typedef __attribute__((ext_vector_type(4))) float f32x4;

#define MFMA16(a, b, c) __builtin_amdgcn_mfma_f32_16x16x32_bf16((a), (b), (c), 0, 0, 0)

__device__ __forceinline__ unsigned short f2bf(float f) {
    union { __hip_bfloat16 h; unsigned short u; } cv;
    cv.h = __float2bfloat16(f);                      // RNE
    return cv.u;
}

// Convert 8 consecutive f32 -> 8 bf16 and store 16B to LDS.
__device__ __forceinline__ void cvt8_store(unsigned short* dst, const float* src) {
    float4 f0 = *(const float4*)(src);
    float4 f1 = *(const float4*)(src + 4);
    unsigned short h[8];
    h[0] = f2bf(f0.x); h[1] = f2bf(f0.y); h[2] = f2bf(f0.z); h[3] = f2bf(f0.w);
    h[4] = f2bf(f1.x); h[5] = f2bf(f1.y); h[6] = f2bf(f1.z); h[7] = f2bf(f1.w);
    *(uint4*)dst = *(const uint4*)h;
}

// ---------------------------------------------------------------------------
// Kernel A: blockIdx.y in {0,1,2}: per-weight GEMM X@W^T (MFMA) + LIF over t,
// bit-packed spike output. blockIdx.y==3: rpb table expansion + zero the
// per-b proj counters (must complete before the fused attn kernel starts;
// same-stream ordering guarantees it).
// ---------------------------------------------------------------------------
__global__ __launch_bounds__(256) void k_qkv_lif(
    const float* __restrict__ x,
    const float* __restrict__ Wq,
    const float* __restrict__ Wk,
    const float* __restrict__ Wv,
    const float* __restrict__ tbl,
    unsigned int* __restrict__ qbits,
    unsigned int* __restrict__ kbits,
    unsigned int* __restrict__ vbits,
    float* __restrict__ rpbx,
    unsigned int* __restrict__ cnt)
{
    if (blockIdx.y == 3) {
        if (blockIdx.x == 0) cnt[threadIdx.x] = 0;   // 256 per-b counters
        // rpb expansion: 262144 elems / 256 blocks = 1024/block = 4/thread
        int base = blockIdx.x * 1024 + threadIdx.x * 4;
        int hh = base >> 16;
        int n = (base >> 8) & 255, m0 = base & 255;
        int zn = n >> 6, yn = (n >> 3) & 7, xn = n & 7;
        float4 o;
#pragma unroll
        for (int i = 0; i < 4; ++i) {
            int m = m0 + i;
            int zm = m >> 6, ym = (m >> 3) & 7, xm = m & 7;
            int ri = (zn - zm + 3) * 225 + (yn - ym + 7) * 15 + (xn - xm + 7);
            ((float*)&o)[i] = tbl[ri * 4 + hh];
        }
        *(float4*)&rpbx[base] = o;
        return;
    }

    __shared__ unsigned short Wl[128 * 136];   // W rows d (N) x cols c (K), pad +8
    __shared__ unsigned short Xl[64 * 136];    // X tile / spike tile (reused)

    const int tid = threadIdx.x;
    const int wv = tid >> 6, lane = tid & 63;
    const int l15 = lane & 15, lh = lane >> 4;
    const int wsel = blockIdx.y;
    const float* W = (wsel == 0) ? Wq : (wsel == 1) ? Wk : Wv;
    unsigned int* bits = (wsel == 0) ? qbits : (wsel == 1) ? kbits : vbits;
    const int B = blockIdx.x;

    {   // stage W (128x128 f32 -> bf16)
#pragma unroll
        for (int i = 0; i < 8; ++i) {
            int e = i * 2048 + tid * 8;
            int r = e >> 7, cc = e & 127;
            cvt8_store(&Wl[r * 136 + cc], W + r * 128 + cc);
        }
    }

    f32x4 vst[8];                                   // LIF membrane, persists over t
#pragma unroll
    for (int nt = 0; nt < 8; ++nt) vst[nt] = (f32x4){0.f, 0.f, 0.f, 0.f};

    for (int t = 0; t < 4; ++t) {
        __syncthreads();                            // Xl free (pack reads done)
        const float* xg = x + t * 2097152 + B * 8192;
#pragma unroll
        for (int i = 0; i < 4; ++i) {
            int e = i * 2048 + tid * 8;
            int r = e >> 7, cc = e & 127;
            cvt8_store(&Xl[r * 136 + cc], xg + r * 128 + cc);
        }
        __syncthreads();

        f32x4 acc[8];
#pragma unroll
        for (int nt = 0; nt < 8; ++nt) acc[nt] = (f32x4){0.f, 0.f, 0.f, 0.f};
#pragma unroll
        for (int kk = 0; kk < 4; ++kk) {
            bf16x8 a = *(const bf16x8*)&Xl[(wv * 16 + l15) * 136 + kk * 32 + lh * 8];
#pragma unroll
            for (int nt = 0; nt < 8; ++nt) {
                bf16x8 b = *(const bf16x8*)&Wl[(nt * 16 + l15) * 136 + kk * 32 + lh * 8];
                acc[nt] = MFMA16(a, b, acc[nt]);
            }
        }
        // LIF: v += (y-v)/2; s=(v>=1); v*=(1-s); spike shorts -> Xl
        unsigned short sp[8][4];
#pragma unroll
        for (int nt = 0; nt < 8; ++nt) {
#pragma unroll
            for (int reg = 0; reg < 4; ++reg) {
                float y = acc[nt][reg];
                float v = vst[nt][reg];
                v = v + (y - v) * 0.5f;
                float s = (v >= 1.0f) ? 1.0f : 0.0f;
                vst[nt][reg] = v * (1.0f - s);
                sp[nt][reg] = (s != 0.0f) ? (unsigned short)1 : (unsigned short)0;
            }
        }
        __syncthreads();                            // all MFMA reads of Xl done
#pragma unroll
        for (int nt = 0; nt < 8; ++nt)
#pragma unroll
            for (int reg = 0; reg < 4; ++reg)
                Xl[(wv * 16 + lh * 4 + reg) * 136 + nt * 16 + l15] = sp[nt][reg];
        __syncthreads();
        // pack: thread u owns n=u: row hw=u>>2, cols (u&3)*32 .. +31 -> 32 bits
        {
            const unsigned short* rowp = &Xl[(tid >> 2) * 136 + (tid & 3) * 32];
            unsigned int mask = 0;
#pragma unroll
            for (int j8 = 0; j8 < 4; ++j8) {
                uint4 u = *(const uint4*)(rowp + j8 * 8);
                int base = j8 * 8;
                if (u.x & 0xFFFFu) mask |= 1u << (base + 0);
                if (u.x >> 16)     mask |= 1u << (base + 1);
                if (u.y & 0xFFFFu) mask |= 1u << (base + 2);
                if (u.y >> 16)     mask |= 1u << (base + 3);
                if (u.z & 0xFFFFu) mask |= 1u << (base + 4);
                if (u.z >> 16)     mask |= 1u << (base + 5);
                if (u.w & 0xFFFFu) mask |= 1u << (base + 6);
                if (u.w >> 16)     mask |= 1u << (base + 7);
            }
            bits[(t * 256 + B) * 256 + tid] = mask;  // coalesced 1KB
        }
    }
}

// ---------------------------------------------------------------------------
// Kernel B (fused attn + proj): one block per group g. Phase 1: attn rows via
// popcount + rpb (f32 NT stores), PV via MFMA -> o_ws. Phase 2: the LAST
// arriver among the 4 groups of b = g>>2 (device-scope atomic counter) runs
// the proj GEMM + LIF for that b. LDS overlaid between phases (51 KB max).
// ---------------------------------------------------------------------------
__global__ __launch_bounds__(256) void k_attn_proj(
    const unsigned int* __restrict__ qbits,
    const unsigned int* __restrict__ kbits,
    const unsigned int* __restrict__ vbits,
    const float* __restrict__ rpbx,
    const float* __restrict__ Wp,
    const float* __restrict__ bp,
    float* __restrict__ attn_out,
    unsigned short* __restrict__ o_ws,
    unsigned int* __restrict__ cnt,
    float* __restrict__ out0)
{
    __shared__ __align__(16) unsigned char smem[52224];
    __shared__ int winner;
    // phase-1 overlay
    unsigned int*   qb    = (unsigned int*)smem;                       //  1024 B
    unsigned short* vT    = (unsigned short*)(smem + 1024);            // 16896 B
    unsigned short* attnL = (unsigned short*)(smem + 17920);           // 16896 B
    // phase-2 overlay (attn data dead by then)
    unsigned short* Wl = (unsigned short*)smem;                        // 34816 B
    unsigned short* Al = (unsigned short*)(smem + 34816);              // 17408 B

    const int tid = threadIdx.x;
    const int wv = tid >> 6, lane = tid & 63;
    const int l15 = lane & 15, lh = lane >> 4;
    const int g = blockIdx.x, hh = g & 3;

    qb[tid] = qbits[g * 256 + tid];
    uint4 km = *(const uint4*)&kbits[g * 256 + (tid & 63) * 4];
    {   // v bits -> bf16 vT[d][m]
        unsigned int vb = vbits[g * 256 + tid];
#pragma unroll
        for (int d = 0; d < 32; ++d)
            vT[d * 264 + tid] = ((vb >> d) & 1u) ? (unsigned short)0x3F80
                                                 : (unsigned short)0;
    }
    __syncthreads();

    const float SC = 0.17677669529663687f;     // 32^-0.5
    float* attn_b = attn_out + (size_t)g * 65536;
    const float* rp = rpbx + hh * 65536;
    unsigned short* ob = o_ws + g * 8192;
    const int rg = wv, m0 = (tid & 63) * 4;
    const int rt = wv >> 1, nh = wv & 1;       // PV work split

    for (int c = 0; c < 8; ++c) {              // 32-row chunks
        // rows n = c*32 + j*4 + rg; thread owns cols m0..m0+3
#pragma unroll
        for (int j = 0; j < 8; ++j) {
            int n = c * 32 + j * 4 + rg;
            unsigned int qn = qb[n];
            float4 rp4 = *(const float4*)&rp[n * 256 + m0];
            f32x4 av;
            av.x = (float)__popc(qn & km.x) * SC + rp4.x;
            av.y = (float)__popc(qn & km.y) * SC + rp4.y;
            av.z = (float)__popc(qn & km.z) * SC + rp4.z;
            av.w = (float)__popc(qn & km.w) * SC + rp4.w;
            __builtin_nontemporal_store(av, (f32x4*)(attn_b + n * 256 + m0));
            unsigned int p0 = (unsigned int)f2bf(av.x) | ((unsigned int)f2bf(av.y) << 16);
            unsigned int p1 = (unsigned int)f2bf(av.z) | ((unsigned int)f2bf(av.w) << 16);
            uint2 pk; pk.x = p0; pk.y = p1;
            *(uint2*)&attnL[(j * 4 + rg) * 264 + m0] = pk;
        }
        __syncthreads();
        // o(32x32) = attnL(32x256) @ v(256x32); wave (rt,nh) -> 16x16 tile
        f32x4 oc = (f32x4){0.f, 0.f, 0.f, 0.f};
#pragma unroll
        for (int kk = 0; kk < 8; ++kk) {
            bf16x8 a = *(const bf16x8*)&attnL[(rt * 16 + l15) * 264 + kk * 32 + lh * 8];
            bf16x8 b = *(const bf16x8*)&vT[(nh * 16 + l15) * 264 + kk * 32 + lh * 8];
            oc = MFMA16(a, b, oc);
        }
#pragma unroll
        for (int reg = 0; reg < 4; ++reg) {
            int n = c * 32 + rt * 16 + lh * 4 + reg;
            ob[n * 32 + nh * 16 + l15] = f2bf(oc[reg]);
        }
        __syncthreads();                        // attnL reuse next chunk
    }

    // ---- arrival protocol: last of the 4 groups of b runs proj ----
    const int b = g >> 2;
    __threadfence();                            // release our o_ws stores (agent)
    __syncthreads();
    if (tid == 0) {
        unsigned int old = atomicAdd(&cnt[b], 1u);   // device-scope (G12)
        winner = (old == 3u) ? 1 : 0;
    }
    __syncthreads();
    if (!winner) return;
    __threadfence();                            // acquire: invalidate stale L1/L2

    // ---- phase 2: proj + LIF for b (identical math to R5's k_proj_lif) ----
    {   // stage Wproj (f32 -> bf16)
#pragma unroll
        for (int i = 0; i < 8; ++i) {
            int e = i * 2048 + tid * 8;
            int r = e >> 7, cc = e & 127;
            cvt8_store(&Wl[r * 136 + cc], Wp + r * 128 + cc);
        }
    }
    float biasf[2];
#pragma unroll
    for (int ntl = 0; ntl < 2; ++ntl)
        biasf[ntl] = bp[(wv * 2 + ntl) * 16 + l15];

    const unsigned short* obp = o_ws + b * 32768;  // o[b][head][n][hd] bf16

    for (int c = 0; c < 4; ++c) {                  // hw group c*16 .. c*16+15
        __syncthreads();
        // Al rows lr2 = t2*16+rit, cols cc = head*32+hd; n = t2*64 + c*16 + rit
#pragma unroll
        for (int i = 0; i < 4; ++i) {
            int e = i * 2048 + tid * 8;
            int lr2 = e >> 7, cc = e & 127;
            int t2 = lr2 >> 4, rit = lr2 & 15;
            int hhh = cc >> 5, hd = cc & 31;
            int n = t2 * 64 + c * 16 + rit;
            *(uint4*)&Al[lr2 * 136 + cc] =
                *(const uint4*)(obp + (hhh * 256 + n) * 32 + hd);
        }
        __syncthreads();

        f32x4 acc[4][2];
#pragma unroll
        for (int t2 = 0; t2 < 4; ++t2)
#pragma unroll
            for (int ntl = 0; ntl < 2; ++ntl)
                acc[t2][ntl] = (f32x4){0.f, 0.f, 0.f, 0.f};
#pragma unroll
        for (int kk = 0; kk < 4; ++kk) {
            bf16x8 a[4];
#pragma unroll
            for (int t2 = 0; t2 < 4; ++t2)
                a[t2] = *(const bf16x8*)&Al[(t2 * 16 + l15) * 136 + kk * 32 + lh * 8];
#pragma unroll
            for (int ntl = 0; ntl < 2; ++ntl) {
                bf16x8 bb = *(const bf16x8*)&Wl[((wv * 2 + ntl) * 16 + l15) * 136 + kk * 32 + lh * 8];
#pragma unroll
                for (int t2 = 0; t2 < 4; ++t2)
                    acc[t2][ntl] = MFMA16(a[t2], bb, acc[t2][ntl]);
            }
        }
        // bias + LIF over t2, store spikes (f32 0/1, nontemporal)
#pragma unroll
        for (int ntl = 0; ntl < 2; ++ntl) {
            int d = (wv * 2 + ntl) * 16 + l15;
#pragma unroll
            for (int reg = 0; reg < 4; ++reg) {
                int hw = c * 16 + lh * 4 + reg;
                float v = 0.f;
#pragma unroll
                for (int t2 = 0; t2 < 4; ++t2) {
                    float y = acc[t2][ntl][reg] + biasf[ntl];
                    v = v + (y - v) * 0.5f;
                    float s = (v >= 1.0f) ? 1.0f : 0.0f;
                    v = v * (1.0f - s);
                    __builtin_nontemporal_store(
                        s, out0 + t2 * 2097152 + b * 8192 + hw * 128 + d);
                }
            }
        }
    }
}

// ---------------------------------------------------------------------------
extern "C" void kernel_launch(void* const* d_in, const int* in_sizes, int n_in,
                              void* d_out, int out_size, void* d_ws, size_t ws_size,
                              hipStream_t stream)
{
    const float* x   = (const float*)d_in[0];
    const float* Wq  = (const float*)d_in[1];
    const float* Wk  = (const float*)d_in[2];
    const float* Wv  = (const float*)d_in[3];
    const float* tbl = (const float*)d_in[4];
    const float* Wp  = (const float*)d_in[5];
    const float* bp  = (const float*)d_in[6];

    float* out0 = (float*)d_out;                                // 8388608 f32
    float* attn = out0 + 8388608;                               // 67108864 f32

    unsigned short* o_ws = (unsigned short*)d_ws;               // 8388608 bf16
    unsigned int* qbits = (unsigned int*)(o_ws + 8388608);      // 262144 u32
    unsigned int* kbits = qbits + 262144;
    unsigned int* vbits = kbits + 262144;
    float* rpbx = (float*)(vbits + 262144);                     // 262144 f32
    unsigned int* cnt = (unsigned int*)(rpbx + 262144);         // 256 u32
    // total ws use: ~21 MB

    k_qkv_lif<<<dim3(256, 4), 256, 0, stream>>>(x, Wq, Wk, Wv, tbl,
                                                qbits, kbits, vbits, rpbx, cnt);
    k_attn_proj<<<1024, 256, 0, stream>>>(qbits, kbits, vbits, rpbx, Wp, bp,
                                          attn, o_ws, cnt, out0);
}

// Round 7
// 372.592 us; speedup vs baseline: 1.6359x; 1.6359x over previous
//
#include <hip/hip_runtime.h>
#include <hip/hip_bf16.h>

// ---------------------------------------------------------------------------
// Spiking Swin block: QKV(+LIF) -> binary attention (+rpb) -> PV -> proj(+LIF)
// I/O: float32. MFMA bf16 16x16x32 for GEMM work (exact for 0/1 spikes).
//
// Index facts (verified by R2/R3/R5/R6 absmax=0):
//  - group g = t*256 + b_old = b_new*4 + head; bits uint32[g][n] over d.
//  - attn flat = (g*256 + n)*256 + m   (f32 output)
//  - out0 flat = t2*2097152 + b_new*8192 + hw*128 + c, n = t2*64 + hw
//
// R6 lesson: device-scope fence/atomic fusion collapsed write BW to 0.93 TB/s
// (7x regression) -> REVERTED to separate kernels. This round: barrier-free
// k_attn. PV A-fragments are computed directly from bit-masks in registers
// (A[m=lane&15][k=(lane>>4)*8+j], verified layout), so attn values never
// round-trip through LDS; the c-loop has no __syncthreads -> NT stores are
// never drained mid-kernel. LDS 18.9 KB -> ~7 blocks/CU.
// ---------------------------------------------------------------------------

typedef __attribute__((ext_vector_type(8))) short bf16x8;   // 8 bf16 = 4 VGPRs
typedef __attribute__((ext_vector_type(4))) float f32x4;

#define MFMA16(a, b, c) __builtin_amdgcn_mfma_f32_16x16x32_bf16((a), (b), (c), 0, 0, 0)

__device__ __forceinline__ unsigned short f2bf(float f) {
    union { __hip_bfloat16 h; unsigned short u; } cv;
    cv.h = __float2bfloat16(f);                      // RNE
    return cv.u;
}

// Convert 8 consecutive f32 -> 8 bf16 and store 16B to LDS.
__device__ __forceinline__ void cvt8_store(unsigned short* dst, const float* src) {
    float4 f0 = *(const float4*)(src);
    float4 f1 = *(const float4*)(src + 4);
    unsigned short h[8];
    h[0] = f2bf(f0.x); h[1] = f2bf(f0.y); h[2] = f2bf(f0.z); h[3] = f2bf(f0.w);
    h[4] = f2bf(f1.x); h[5] = f2bf(f1.y); h[6] = f2bf(f1.z); h[7] = f2bf(f1.w);
    *(uint4*)dst = *(const uint4*)h;
}

// ---------------------------------------------------------------------------
// Kernel A: blockIdx.y in {0,1,2}: per-weight GEMM X@W^T (MFMA) + LIF over t,
// bit-packed spike output. blockIdx.y==3: rpb table expansion.
// ---------------------------------------------------------------------------
__global__ __launch_bounds__(256) void k_qkv_lif(
    const float* __restrict__ x,
    const float* __restrict__ Wq,
    const float* __restrict__ Wk,
    const float* __restrict__ Wv,
    const float* __restrict__ tbl,
    unsigned int* __restrict__ qbits,
    unsigned int* __restrict__ kbits,
    unsigned int* __restrict__ vbits,
    float* __restrict__ rpbx)
{
    if (blockIdx.y == 3) {
        // rpb expansion: 262144 elems / 256 blocks = 1024/block = 4/thread
        int base = blockIdx.x * 1024 + threadIdx.x * 4;
        int hh = base >> 16;
        int n = (base >> 8) & 255, m0 = base & 255;
        int zn = n >> 6, yn = (n >> 3) & 7, xn = n & 7;
        float4 o;
#pragma unroll
        for (int i = 0; i < 4; ++i) {
            int m = m0 + i;
            int zm = m >> 6, ym = (m >> 3) & 7, xm = m & 7;
            int ri = (zn - zm + 3) * 225 + (yn - ym + 7) * 15 + (xn - xm + 7);
            ((float*)&o)[i] = tbl[ri * 4 + hh];
        }
        *(float4*)&rpbx[base] = o;
        return;
    }

    __shared__ unsigned short Wl[128 * 136];   // W rows d (N) x cols c (K), pad +8
    __shared__ unsigned short Xl[64 * 136];    // X tile / spike tile (reused)

    const int tid = threadIdx.x;
    const int wv = tid >> 6, lane = tid & 63;
    const int l15 = lane & 15, lh = lane >> 4;
    const int wsel = blockIdx.y;
    const float* W = (wsel == 0) ? Wq : (wsel == 1) ? Wk : Wv;
    unsigned int* bits = (wsel == 0) ? qbits : (wsel == 1) ? kbits : vbits;
    const int B = blockIdx.x;

    {   // stage W (128x128 f32 -> bf16)
#pragma unroll
        for (int i = 0; i < 8; ++i) {
            int e = i * 2048 + tid * 8;
            int r = e >> 7, cc = e & 127;
            cvt8_store(&Wl[r * 136 + cc], W + r * 128 + cc);
        }
    }

    f32x4 vst[8];                                   // LIF membrane, persists over t
#pragma unroll
    for (int nt = 0; nt < 8; ++nt) vst[nt] = (f32x4){0.f, 0.f, 0.f, 0.f};

    for (int t = 0; t < 4; ++t) {
        __syncthreads();                            // Xl free (pack reads done)
        const float* xg = x + t * 2097152 + B * 8192;
#pragma unroll
        for (int i = 0; i < 4; ++i) {
            int e = i * 2048 + tid * 8;
            int r = e >> 7, cc = e & 127;
            cvt8_store(&Xl[r * 136 + cc], xg + r * 128 + cc);
        }
        __syncthreads();

        f32x4 acc[8];
#pragma unroll
        for (int nt = 0; nt < 8; ++nt) acc[nt] = (f32x4){0.f, 0.f, 0.f, 0.f};
#pragma unroll
        for (int kk = 0; kk < 4; ++kk) {
            bf16x8 a = *(const bf16x8*)&Xl[(wv * 16 + l15) * 136 + kk * 32 + lh * 8];
#pragma unroll
            for (int nt = 0; nt < 8; ++nt) {
                bf16x8 b = *(const bf16x8*)&Wl[(nt * 16 + l15) * 136 + kk * 32 + lh * 8];
                acc[nt] = MFMA16(a, b, acc[nt]);
            }
        }
        // LIF: v += (y-v)/2; s=(v>=1); v*=(1-s); spike shorts -> Xl
        unsigned short sp[8][4];
#pragma unroll
        for (int nt = 0; nt < 8; ++nt) {
#pragma unroll
            for (int reg = 0; reg < 4; ++reg) {
                float y = acc[nt][reg];
                float v = vst[nt][reg];
                v = v + (y - v) * 0.5f;
                float s = (v >= 1.0f) ? 1.0f : 0.0f;
                vst[nt][reg] = v * (1.0f - s);
                sp[nt][reg] = (s != 0.0f) ? (unsigned short)1 : (unsigned short)0;
            }
        }
        __syncthreads();                            // all MFMA reads of Xl done
#pragma unroll
        for (int nt = 0; nt < 8; ++nt)
#pragma unroll
            for (int reg = 0; reg < 4; ++reg)
                Xl[(wv * 16 + lh * 4 + reg) * 136 + nt * 16 + l15] = sp[nt][reg];
        __syncthreads();
        // pack: thread u owns n=u: row hw=u>>2, cols (u&3)*32 .. +31 -> 32 bits
        {
            const unsigned short* rowp = &Xl[(tid >> 2) * 136 + (tid & 3) * 32];
            unsigned int mask = 0;
#pragma unroll
            for (int j8 = 0; j8 < 4; ++j8) {
                uint4 u = *(const uint4*)(rowp + j8 * 8);
                int base = j8 * 8;
                if (u.x & 0xFFFFu) mask |= 1u << (base + 0);
                if (u.x >> 16)     mask |= 1u << (base + 1);
                if (u.y & 0xFFFFu) mask |= 1u << (base + 2);
                if (u.y >> 16)     mask |= 1u << (base + 3);
                if (u.z & 0xFFFFu) mask |= 1u << (base + 4);
                if (u.z >> 16)     mask |= 1u << (base + 5);
                if (u.w & 0xFFFFu) mask |= 1u << (base + 6);
                if (u.w >> 16)     mask |= 1u << (base + 7);
            }
            bits[(t * 256 + B) * 256 + tid] = mask;  // coalesced 1KB
        }
    }
}

// ---------------------------------------------------------------------------
// Kernel B: one block per group g. BARRIER-FREE main body:
//   phase a) attn f32 NT stores: thread owns (rows n=c*32+j*4+wv, cols m0..+3),
//            values = popc(qb[n]&km)*SC + rp, straight from registers.
//   phase b) PV: o(256x32) = attn @ v. A-fragments rebuilt IN REGISTERS from
//            qb/kb bitmasks (A[m=lane&15][k=(lane>>4)*8+j]); B from vT LDS.
// qb/kb/vT are read-only after a single staging barrier -> no vmcnt drains.
// LDS 18.9 KB -> ~7 blocks/CU.
// ---------------------------------------------------------------------------
__global__ __launch_bounds__(256) void k_attn(
    const unsigned int* __restrict__ qbits,
    const unsigned int* __restrict__ kbits,
    const unsigned int* __restrict__ vbits,
    const float* __restrict__ rpbx,
    float* __restrict__ attn_out,
    unsigned short* __restrict__ o_ws)
{
    __shared__ unsigned int  qb[256];          // q row bitmasks
    __shared__ unsigned int  kb[256];          // k row bitmasks
    __shared__ unsigned short vT[32 * 264];    // v transposed: [d][m], pad +8

    const int tid = threadIdx.x;
    const int wv = tid >> 6, lane = tid & 63;
    const int l15 = lane & 15, lh = lane >> 4;
    const int g = blockIdx.x, hh = g & 3;

    qb[tid] = qbits[g * 256 + tid];
    kb[tid] = kbits[g * 256 + tid];
    uint4 km = *(const uint4*)&kbits[g * 256 + (tid & 63) * 4];
    {   // v bits -> bf16 vT[d][m]
        unsigned int vb = vbits[g * 256 + tid];
#pragma unroll
        for (int d = 0; d < 32; ++d)
            vT[d * 264 + tid] = ((vb >> d) & 1u) ? (unsigned short)0x3F80
                                                 : (unsigned short)0;
    }
    __syncthreads();                           // the ONLY barrier

    const float SC = 0.17677669529663687f;     // 32^-0.5
    float* attn_b = attn_out + (size_t)g * 65536;
    const float* rp = rpbx + hh * 65536;
    unsigned short* ob = o_ws + g * 8192;
    const int m0 = (tid & 63) * 4;

    // ---- phase a: attn f32 NT stores, no LDS involvement ----
#pragma unroll 4
    for (int i = 0; i < 64; ++i) {             // n = i*4 + wv
        int n = i * 4 + wv;
        unsigned int qn = qb[n];
        float4 rp4 = *(const float4*)&rp[n * 256 + m0];
        f32x4 av;
        av.x = (float)__popc(qn & km.x) * SC + rp4.x;
        av.y = (float)__popc(qn & km.y) * SC + rp4.y;
        av.z = (float)__popc(qn & km.z) * SC + rp4.z;
        av.w = (float)__popc(qn & km.w) * SC + rp4.w;
        __builtin_nontemporal_store(av, (f32x4*)(attn_b + n * 256 + m0));
    }

    // ---- phase b: PV with register-built A-fragments ----
    // wave wv owns rows [wv*64, wv*64+64): 4 tiles of 16 rows.
#pragma unroll
    for (int tt = 0; tt < 4; ++tt) {
        const int nrow = wv * 64 + tt * 16 + l15;       // A row m=l15
        const unsigned int qn = qb[nrow];
        const float* rprow = rp + nrow * 256;
        f32x4 oc0 = (f32x4){0.f, 0.f, 0.f, 0.f};
        f32x4 oc1 = (f32x4){0.f, 0.f, 0.f, 0.f};
#pragma unroll
        for (int kk = 0; kk < 8; ++kk) {
            const int k0 = kk * 32 + lh * 8;            // K base for this lane
            // rebuild A-fragment: a[j] = attn[nrow][k0+j] in bf16
            unsigned short af[8];
            float4 r0 = *(const float4*)&rprow[k0];
            float4 r1 = *(const float4*)&rprow[k0 + 4];
            af[0] = f2bf((float)__popc(qn & kb[k0 + 0]) * SC + r0.x);
            af[1] = f2bf((float)__popc(qn & kb[k0 + 1]) * SC + r0.y);
            af[2] = f2bf((float)__popc(qn & kb[k0 + 2]) * SC + r0.z);
            af[3] = f2bf((float)__popc(qn & kb[k0 + 3]) * SC + r0.w);
            af[4] = f2bf((float)__popc(qn & kb[k0 + 4]) * SC + r1.x);
            af[5] = f2bf((float)__popc(qn & kb[k0 + 5]) * SC + r1.y);
            af[6] = f2bf((float)__popc(qn & kb[k0 + 6]) * SC + r1.z);
            af[7] = f2bf((float)__popc(qn & kb[k0 + 7]) * SC + r1.w);
            bf16x8 a = *(const bf16x8*)af;
            bf16x8 b0 = *(const bf16x8*)&vT[l15 * 264 + k0];        // d 0..15
            bf16x8 b1 = *(const bf16x8*)&vT[(16 + l15) * 264 + k0]; // d 16..31
            oc0 = MFMA16(a, b0, oc0);
            oc1 = MFMA16(a, b1, oc1);
        }
#pragma unroll
        for (int reg = 0; reg < 4; ++reg) {
            int n = wv * 64 + tt * 16 + lh * 4 + reg;   // C row = quad*4+reg
            ob[n * 32 + l15]      = f2bf(oc0[reg]);
            ob[n * 32 + 16 + l15] = f2bf(oc1[reg]);
        }
    }
}

// ---------------------------------------------------------------------------
// Kernel C: per b_new: gather o across heads -> A(256x128); Y = A@Wp^T + bias;
// LIF over t2 (rows n = t2*64 + hw). Chunked by hw (4 chunks of 16) so each
// wave holds all 4 timesteps of its elements in accumulators.
// ---------------------------------------------------------------------------
__global__ __launch_bounds__(256) void k_proj_lif(
    const unsigned short* __restrict__ o_ws,
    const float* __restrict__ Wp,
    const float* __restrict__ bp,
    float* __restrict__ out0)
{
    __shared__ unsigned short Wl[128 * 136];
    __shared__ unsigned short Al[64 * 136];

    const int tid = threadIdx.x;
    const int wv = tid >> 6, lane = tid & 63;
    const int l15 = lane & 15, lh = lane >> 4;
    const int b = blockIdx.x;

    {   // stage Wproj (f32 -> bf16)
#pragma unroll
        for (int i = 0; i < 8; ++i) {
            int e = i * 2048 + tid * 8;
            int r = e >> 7, cc = e & 127;
            cvt8_store(&Wl[r * 136 + cc], Wp + r * 128 + cc);
        }
    }

    float biasf[2];
#pragma unroll
    for (int ntl = 0; ntl < 2; ++ntl)
        biasf[ntl] = bp[(wv * 2 + ntl) * 16 + l15];

    const unsigned short* ob = o_ws + b * 32768;   // o[b][head][n][hd] bf16

    for (int c = 0; c < 4; ++c) {                  // hw group c*16 .. c*16+15
        __syncthreads();
        // Al rows lr2 = t2*16+rit, cols cc = head*32+hd; n = t2*64 + c*16 + rit
#pragma unroll
        for (int i = 0; i < 4; ++i) {
            int e = i * 2048 + tid * 8;
            int lr2 = e >> 7, cc = e & 127;
            int t2 = lr2 >> 4, rit = lr2 & 15;
            int hhh = cc >> 5, hd = cc & 31;
            int n = t2 * 64 + c * 16 + rit;
            *(uint4*)&Al[lr2 * 136 + cc] =
                *(const uint4*)(ob + (hhh * 256 + n) * 32 + hd);
        }
        __syncthreads();

        f32x4 acc[4][2];
#pragma unroll
        for (int t2 = 0; t2 < 4; ++t2)
#pragma unroll
            for (int ntl = 0; ntl < 2; ++ntl)
                acc[t2][ntl] = (f32x4){0.f, 0.f, 0.f, 0.f};
#pragma unroll
        for (int kk = 0; kk < 4; ++kk) {
            bf16x8 a[4];
#pragma unroll
            for (int t2 = 0; t2 < 4; ++t2)
                a[t2] = *(const bf16x8*)&Al[(t2 * 16 + l15) * 136 + kk * 32 + lh * 8];
#pragma unroll
            for (int ntl = 0; ntl < 2; ++ntl) {
                bf16x8 bb = *(const bf16x8*)&Wl[((wv * 2 + ntl) * 16 + l15) * 136 + kk * 32 + lh * 8];
#pragma unroll
                for (int t2 = 0; t2 < 4; ++t2)
                    acc[t2][ntl] = MFMA16(a[t2], bb, acc[t2][ntl]);
            }
        }
        // bias + LIF over t2, store spikes (f32 0/1, nontemporal)
#pragma unroll
        for (int ntl = 0; ntl < 2; ++ntl) {
            int d = (wv * 2 + ntl) * 16 + l15;
#pragma unroll
            for (int reg = 0; reg < 4; ++reg) {
                int hw = c * 16 + lh * 4 + reg;
                float v = 0.f;
#pragma unroll
                for (int t2 = 0; t2 < 4; ++t2) {
                    float y = acc[t2][ntl][reg] + biasf[ntl];
                    v = v + (y - v) * 0.5f;
                    float s = (v >= 1.0f) ? 1.0f : 0.0f;
                    v = v * (1.0f - s);
                    __builtin_nontemporal_store(
                        s, out0 + t2 * 2097152 + b * 8192 + hw * 128 + d);
                }
            }
        }
    }
}

// ---------------------------------------------------------------------------
extern "C" void kernel_launch(void* const* d_in, const int* in_sizes, int n_in,
                              void* d_out, int out_size, void* d_ws, size_t ws_size,
                              hipStream_t stream)
{
    const float* x   = (const float*)d_in[0];
    const float* Wq  = (const float*)d_in[1];
    const float* Wk  = (const float*)d_in[2];
    const float* Wv  = (const float*)d_in[3];
    const float* tbl = (const float*)d_in[4];
    const float* Wp  = (const float*)d_in[5];
    const float* bp  = (const float*)d_in[6];

    float* out0 = (float*)d_out;                                // 8388608 f32
    float* attn = out0 + 8388608;                               // 67108864 f32

    unsigned short* o_ws = (unsigned short*)d_ws;               // 8388608 bf16
    unsigned int* qbits = (unsigned int*)(o_ws + 8388608);      // 262144 u32
    unsigned int* kbits = qbits + 262144;
    unsigned int* vbits = kbits + 262144;
    float* rpbx = (float*)(vbits + 262144);                     // 262144 f32
    // total ws use: ~21 MB

    k_qkv_lif<<<dim3(256, 4), 256, 0, stream>>>(x, Wq, Wk, Wv, tbl,
                                                qbits, kbits, vbits, rpbx);
    k_attn<<<1024, 256, 0, stream>>>(qbits, kbits, vbits, rpbx, attn, o_ws);
    k_proj_lif<<<256, 256, 0, stream>>>(o_ws, Wp, bp, out0);
}

// Round 8
// 354.434 us; speedup vs baseline: 1.7197x; 1.0512x over previous
//
#include <hip/hip_runtime.h>
#include <hip/hip_bf16.h>

// ---------------------------------------------------------------------------
// Spiking Swin block: QKV(+LIF) -> binary attention (+rpb) -> PV -> proj(+LIF)
// I/O: float32. MFMA bf16 16x16x32 for GEMM work (exact for 0/1 spikes).
//
// Index facts (verified by R2/R3/R5/R6/R7 absmax=0):
//  - group g = t*256 + b_old = b_new*4 + head; bits uint32[g][n] over d.
//  - attn flat = (g*256 + n)*256 + m   (f32 output)
//  - out0 flat = t2*2097152 + b_new*8192 + hw*128 + c, n = t2*64 + hw
//
// R6 lesson: device-scope fence fusion -> 7x regression (reverted).
// R7 lesson: recomputing PV A-frags from bits (barrier-free) -> +20 us
// (scattered rp re-reads + f2bf VALU cost > barrier cost). Reverted.
// This round: R5 structure + double-buffered attnL (8 barriers instead of
// 16; MFMA on chunk c overlaps popc/NT-stores of chunk c+1).
// ---------------------------------------------------------------------------

typedef __attribute__((ext_vector_type(8))) short bf16x8;   // 8 bf16 = 4 VGPRs
typedef __attribute__((ext_vector_type(4))) float f32x4;

#define MFMA16(a, b, c) __builtin_amdgcn_mfma_f32_16x16x32_bf16((a), (b), (c), 0, 0, 0)

__device__ __forceinline__ unsigned short f2bf(float f) {
    union { __hip_bfloat16 h; unsigned short u; } cv;
    cv.h = __float2bfloat16(f);                      // RNE
    return cv.u;
}

// Convert 8 consecutive f32 -> 8 bf16 and store 16B to LDS.
__device__ __forceinline__ void cvt8_store(unsigned short* dst, const float* src) {
    float4 f0 = *(const float4*)(src);
    float4 f1 = *(const float4*)(src + 4);
    unsigned short h[8];
    h[0] = f2bf(f0.x); h[1] = f2bf(f0.y); h[2] = f2bf(f0.z); h[3] = f2bf(f0.w);
    h[4] = f2bf(f1.x); h[5] = f2bf(f1.y); h[6] = f2bf(f1.z); h[7] = f2bf(f1.w);
    *(uint4*)dst = *(const uint4*)h;
}

// ---------------------------------------------------------------------------
// Kernel A: blockIdx.y in {0,1,2}: per-weight GEMM X@W^T (MFMA) + LIF over t,
// bit-packed spike output. blockIdx.y==3: rpb table expansion.
// ---------------------------------------------------------------------------
__global__ __launch_bounds__(256) void k_qkv_lif(
    const float* __restrict__ x,
    const float* __restrict__ Wq,
    const float* __restrict__ Wk,
    const float* __restrict__ Wv,
    const float* __restrict__ tbl,
    unsigned int* __restrict__ qbits,
    unsigned int* __restrict__ kbits,
    unsigned int* __restrict__ vbits,
    float* __restrict__ rpbx)
{
    if (blockIdx.y == 3) {
        // rpb expansion: 262144 elems / 256 blocks = 1024/block = 4/thread
        int base = blockIdx.x * 1024 + threadIdx.x * 4;
        int hh = base >> 16;
        int n = (base >> 8) & 255, m0 = base & 255;
        int zn = n >> 6, yn = (n >> 3) & 7, xn = n & 7;
        float4 o;
#pragma unroll
        for (int i = 0; i < 4; ++i) {
            int m = m0 + i;
            int zm = m >> 6, ym = (m >> 3) & 7, xm = m & 7;
            int ri = (zn - zm + 3) * 225 + (yn - ym + 7) * 15 + (xn - xm + 7);
            ((float*)&o)[i] = tbl[ri * 4 + hh];
        }
        *(float4*)&rpbx[base] = o;
        return;
    }

    __shared__ unsigned short Wl[128 * 136];   // W rows d (N) x cols c (K), pad +8
    __shared__ unsigned short Xl[64 * 136];    // X tile / spike tile (reused)

    const int tid = threadIdx.x;
    const int wv = tid >> 6, lane = tid & 63;
    const int l15 = lane & 15, lh = lane >> 4;
    const int wsel = blockIdx.y;
    const float* W = (wsel == 0) ? Wq : (wsel == 1) ? Wk : Wv;
    unsigned int* bits = (wsel == 0) ? qbits : (wsel == 1) ? kbits : vbits;
    const int B = blockIdx.x;

    {   // stage W (128x128 f32 -> bf16)
#pragma unroll
        for (int i = 0; i < 8; ++i) {
            int e = i * 2048 + tid * 8;
            int r = e >> 7, cc = e & 127;
            cvt8_store(&Wl[r * 136 + cc], W + r * 128 + cc);
        }
    }

    f32x4 vst[8];                                   // LIF membrane, persists over t
#pragma unroll
    for (int nt = 0; nt < 8; ++nt) vst[nt] = (f32x4){0.f, 0.f, 0.f, 0.f};

    for (int t = 0; t < 4; ++t) {
        __syncthreads();                            // Xl free (pack reads done)
        const float* xg = x + t * 2097152 + B * 8192;
#pragma unroll
        for (int i = 0; i < 4; ++i) {
            int e = i * 2048 + tid * 8;
            int r = e >> 7, cc = e & 127;
            cvt8_store(&Xl[r * 136 + cc], xg + r * 128 + cc);
        }
        __syncthreads();

        f32x4 acc[8];
#pragma unroll
        for (int nt = 0; nt < 8; ++nt) acc[nt] = (f32x4){0.f, 0.f, 0.f, 0.f};
#pragma unroll
        for (int kk = 0; kk < 4; ++kk) {
            bf16x8 a = *(const bf16x8*)&Xl[(wv * 16 + l15) * 136 + kk * 32 + lh * 8];
#pragma unroll
            for (int nt = 0; nt < 8; ++nt) {
                bf16x8 b = *(const bf16x8*)&Wl[(nt * 16 + l15) * 136 + kk * 32 + lh * 8];
                acc[nt] = MFMA16(a, b, acc[nt]);
            }
        }
        // LIF: v += (y-v)/2; s=(v>=1); v*=(1-s); spike shorts -> Xl
        unsigned short sp[8][4];
#pragma unroll
        for (int nt = 0; nt < 8; ++nt) {
#pragma unroll
            for (int reg = 0; reg < 4; ++reg) {
                float y = acc[nt][reg];
                float v = vst[nt][reg];
                v = v + (y - v) * 0.5f;
                float s = (v >= 1.0f) ? 1.0f : 0.0f;
                vst[nt][reg] = v * (1.0f - s);
                sp[nt][reg] = (s != 0.0f) ? (unsigned short)1 : (unsigned short)0;
            }
        }
        __syncthreads();                            // all MFMA reads of Xl done
#pragma unroll
        for (int nt = 0; nt < 8; ++nt)
#pragma unroll
            for (int reg = 0; reg < 4; ++reg)
                Xl[(wv * 16 + lh * 4 + reg) * 136 + nt * 16 + l15] = sp[nt][reg];
        __syncthreads();
        // pack: thread u owns n=u: row hw=u>>2, cols (u&3)*32 .. +31 -> 32 bits
        {
            const unsigned short* rowp = &Xl[(tid >> 2) * 136 + (tid & 3) * 32];
            unsigned int mask = 0;
#pragma unroll
            for (int j8 = 0; j8 < 4; ++j8) {
                uint4 u = *(const uint4*)(rowp + j8 * 8);
                int base = j8 * 8;
                if (u.x & 0xFFFFu) mask |= 1u << (base + 0);
                if (u.x >> 16)     mask |= 1u << (base + 1);
                if (u.y & 0xFFFFu) mask |= 1u << (base + 2);
                if (u.y >> 16)     mask |= 1u << (base + 3);
                if (u.z & 0xFFFFu) mask |= 1u << (base + 4);
                if (u.z >> 16)     mask |= 1u << (base + 5);
                if (u.w & 0xFFFFu) mask |= 1u << (base + 6);
                if (u.w >> 16)     mask |= 1u << (base + 7);
            }
            bits[(t * 256 + B) * 256 + tid] = mask;  // coalesced 1KB
        }
    }
}

// ---------------------------------------------------------------------------
// Kernel B: one block per group g. attn[n][m] = popc(q&k)*SC + rpb, f32 NT
// stores; bf16 copy into DOUBLE-BUFFERED attnL; o = attn@v via MFMA.
// One barrier per 32-row chunk: MFMA on buf[c&1] overlaps stores into
// buf[(c+1)&1]. Buffer reuse is 2 iterations apart; the intervening
// barrier's lgkm drain protects it. PV: wave (rt=wv>>1, nh=wv&1).
// LDS 51.7 KB -> 3 blocks/CU.
// ---------------------------------------------------------------------------
__global__ __launch_bounds__(256) void k_attn(
    const unsigned int* __restrict__ qbits,
    const unsigned int* __restrict__ kbits,
    const unsigned int* __restrict__ vbits,
    const float* __restrict__ rpbx,
    float* __restrict__ attn_out,
    unsigned short* __restrict__ o_ws)
{
    __shared__ unsigned int  qb[256];           // q row bitmasks
    __shared__ unsigned short vT[32 * 264];     // v transposed: [d][m], pad +8
    __shared__ unsigned short attnL[2][32 * 264]; // dbuf attn chunk bf16

    const int tid = threadIdx.x;
    const int wv = tid >> 6, lane = tid & 63;
    const int l15 = lane & 15, lh = lane >> 4;
    const int g = blockIdx.x, hh = g & 3;

    qb[tid] = qbits[g * 256 + tid];
    uint4 km = *(const uint4*)&kbits[g * 256 + (tid & 63) * 4];
    {   // v bits -> bf16 vT[d][m]
        unsigned int vb = vbits[g * 256 + tid];
#pragma unroll
        for (int d = 0; d < 32; ++d)
            vT[d * 264 + tid] = ((vb >> d) & 1u) ? (unsigned short)0x3F80
                                                 : (unsigned short)0;
    }
    __syncthreads();

    const float SC = 0.17677669529663687f;      // 32^-0.5
    float* attn_b = attn_out + (size_t)g * 65536;
    const float* rp = rpbx + hh * 65536;
    unsigned short* ob = o_ws + g * 8192;
    const int rg = wv, m0 = (tid & 63) * 4;
    const int rt = wv >> 1, nh = wv & 1;        // PV work split

    for (int c = 0; c < 8; ++c) {               // 32-row chunks, dbuf
        unsigned short* buf = attnL[c & 1];
        // rows n = c*32 + j*4 + rg; thread owns cols m0..m0+3
#pragma unroll
        for (int j = 0; j < 8; ++j) {
            int n = c * 32 + j * 4 + rg;
            unsigned int qn = qb[n];
            float4 rp4 = *(const float4*)&rp[n * 256 + m0];
            f32x4 av;
            av.x = (float)__popc(qn & km.x) * SC + rp4.x;
            av.y = (float)__popc(qn & km.y) * SC + rp4.y;
            av.z = (float)__popc(qn & km.z) * SC + rp4.z;
            av.w = (float)__popc(qn & km.w) * SC + rp4.w;
            __builtin_nontemporal_store(av, (f32x4*)(attn_b + n * 256 + m0));
            unsigned int p0 = (unsigned int)f2bf(av.x) | ((unsigned int)f2bf(av.y) << 16);
            unsigned int p1 = (unsigned int)f2bf(av.z) | ((unsigned int)f2bf(av.w) << 16);
            uint2 pk; pk.x = p0; pk.y = p1;
            *(uint2*)&buf[(j * 4 + rg) * 264 + m0] = pk;
        }
        __syncthreads();                        // buf ready (single barrier/chunk)
        // o(32x32) = buf(32x256) @ v(256x32); wave (rt,nh) -> 16x16 tile
        f32x4 oc = (f32x4){0.f, 0.f, 0.f, 0.f};
#pragma unroll
        for (int kk = 0; kk < 8; ++kk) {
            bf16x8 a = *(const bf16x8*)&buf[(rt * 16 + l15) * 264 + kk * 32 + lh * 8];
            bf16x8 b = *(const bf16x8*)&vT[(nh * 16 + l15) * 264 + kk * 32 + lh * 8];
            oc = MFMA16(a, b, oc);
        }
#pragma unroll
        for (int reg = 0; reg < 4; ++reg) {
            int n = c * 32 + rt * 16 + lh * 4 + reg;
            ob[n * 32 + nh * 16 + l15] = f2bf(oc[reg]);
        }
        // no trailing barrier: next chunk writes the OTHER buffer
    }
}

// ---------------------------------------------------------------------------
// Kernel C: per b_new: gather o across heads -> A(256x128); Y = A@Wp^T + bias;
// LIF over t2 (rows n = t2*64 + hw). Chunked by hw (4 chunks of 16) so each
// wave holds all 4 timesteps of its elements in accumulators.
// ---------------------------------------------------------------------------
__global__ __launch_bounds__(256) void k_proj_lif(
    const unsigned short* __restrict__ o_ws,
    const float* __restrict__ Wp,
    const float* __restrict__ bp,
    float* __restrict__ out0)
{
    __shared__ unsigned short Wl[128 * 136];
    __shared__ unsigned short Al[64 * 136];

    const int tid = threadIdx.x;
    const int wv = tid >> 6, lane = tid & 63;
    const int l15 = lane & 15, lh = lane >> 4;
    const int b = blockIdx.x;

    {   // stage Wproj (f32 -> bf16)
#pragma unroll
        for (int i = 0; i < 8; ++i) {
            int e = i * 2048 + tid * 8;
            int r = e >> 7, cc = e & 127;
            cvt8_store(&Wl[r * 136 + cc], Wp + r * 128 + cc);
        }
    }

    float biasf[2];
#pragma unroll
    for (int ntl = 0; ntl < 2; ++ntl)
        biasf[ntl] = bp[(wv * 2 + ntl) * 16 + l15];

    const unsigned short* ob = o_ws + b * 32768;   // o[b][head][n][hd] bf16

    for (int c = 0; c < 4; ++c) {                  // hw group c*16 .. c*16+15
        __syncthreads();
        // Al rows lr2 = t2*16+rit, cols cc = head*32+hd; n = t2*64 + c*16 + rit
#pragma unroll
        for (int i = 0; i < 4; ++i) {
            int e = i * 2048 + tid * 8;
            int lr2 = e >> 7, cc = e & 127;
            int t2 = lr2 >> 4, rit = lr2 & 15;
            int hhh = cc >> 5, hd = cc & 31;
            int n = t2 * 64 + c * 16 + rit;
            *(uint4*)&Al[lr2 * 136 + cc] =
                *(const uint4*)(ob + (hhh * 256 + n) * 32 + hd);
        }
        __syncthreads();

        f32x4 acc[4][2];
#pragma unroll
        for (int t2 = 0; t2 < 4; ++t2)
#pragma unroll
            for (int ntl = 0; ntl < 2; ++ntl)
                acc[t2][ntl] = (f32x4){0.f, 0.f, 0.f, 0.f};
#pragma unroll
        for (int kk = 0; kk < 4; ++kk) {
            bf16x8 a[4];
#pragma unroll
            for (int t2 = 0; t2 < 4; ++t2)
                a[t2] = *(const bf16x8*)&Al[(t2 * 16 + l15) * 136 + kk * 32 + lh * 8];
#pragma unroll
            for (int ntl = 0; ntl < 2; ++ntl) {
                bf16x8 bb = *(const bf16x8*)&Wl[((wv * 2 + ntl) * 16 + l15) * 136 + kk * 32 + lh * 8];
#pragma unroll
                for (int t2 = 0; t2 < 4; ++t2)
                    acc[t2][ntl] = MFMA16(a[t2], bb, acc[t2][ntl]);
            }
        }
        // bias + LIF over t2, store spikes (f32 0/1, nontemporal)
#pragma unroll
        for (int ntl = 0; ntl < 2; ++ntl) {
            int d = (wv * 2 + ntl) * 16 + l15;
#pragma unroll
            for (int reg = 0; reg < 4; ++reg) {
                int hw = c * 16 + lh * 4 + reg;
                float v = 0.f;
#pragma unroll
                for (int t2 = 0; t2 < 4; ++t2) {
                    float y = acc[t2][ntl][reg] + biasf[ntl];
                    v = v + (y - v) * 0.5f;
                    float s = (v >= 1.0f) ? 1.0f : 0.0f;
                    v = v * (1.0f - s);
                    __builtin_nontemporal_store(
                        s, out0 + t2 * 2097152 + b * 8192 + hw * 128 + d);
                }
            }
        }
    }
}

// ---------------------------------------------------------------------------
extern "C" void kernel_launch(void* const* d_in, const int* in_sizes, int n_in,
                              void* d_out, int out_size, void* d_ws, size_t ws_size,
                              hipStream_t stream)
{
    const float* x   = (const float*)d_in[0];
    const float* Wq  = (const float*)d_in[1];
    const float* Wk  = (const float*)d_in[2];
    const float* Wv  = (const float*)d_in[3];
    const float* tbl = (const float*)d_in[4];
    const float* Wp  = (const float*)d_in[5];
    const float* bp  = (const float*)d_in[6];

    float* out0 = (float*)d_out;                                // 8388608 f32
    float* attn = out0 + 8388608;                               // 67108864 f32

    unsigned short* o_ws = (unsigned short*)d_ws;               // 8388608 bf16
    unsigned int* qbits = (unsigned int*)(o_ws + 8388608);      // 262144 u32
    unsigned int* kbits = qbits + 262144;
    unsigned int* vbits = kbits + 262144;
    float* rpbx = (float*)(vbits + 262144);                     // 262144 f32
    // total ws use: ~21 MB

    k_qkv_lif<<<dim3(256, 4), 256, 0, stream>>>(x, Wq, Wk, Wv, tbl,
                                                qbits, kbits, vbits, rpbx);
    k_attn<<<1024, 256, 0, stream>>>(qbits, kbits, vbits, rpbx, attn, o_ws);
    k_proj_lif<<<256, 256, 0, stream>>>(o_ws, Wp, bp, out0);
}